// Round 10
// baseline (261.381 us; speedup 1.0000x reference)
//
#include <hip/hip_runtime.h>
#include <cfloat>
#include <climits>

#define NEG 0.2f
#define GEPS 1e-5f
#define D 6
#define H 13   // 2*D+1
#define KOUT 16

#define MPAD 8192      // padded candidate capacity (PF*64 aligned)
#define NITER (MPAD/64)
#define PF 8           // prefetch depth (register pipeline)
#define QW 4           // queries per wave
#define QBLK 16        // queries per block (4 waves)
#define CAP 64         // survivor slots per query
#define MARGIN 0.05f   // e-space margin covering fma-vs-reference rounding

__device__ __forceinline__ float lrelu(float x){ return x >= 0.f ? x : NEG*x; }

// atoms (n,3) -> P {x,y,z,|c|^2}, padded with never-selected sentinels
__global__ void pack_kernel(const float* __restrict__ xyz,
                            float4* __restrict__ P, int n, int npad){
  int i = blockIdx.x*blockDim.x + threadIdx.x;
  if (i >= npad) return;
  if (i < n){
    float x = xyz[3*i], y = xyz[3*i+1], z = xyz[3*i+2];
    float sq;
    {
#pragma clang fp contract(off)
      sq = (x*x + y*y) + z*z;
    }
    P[i] = make_float4(x,y,z,sq);
  } else {
    P[i] = make_float4(0.f,0.f,0.f,1e30f);  // e = 1e30 -> never a min/survivor
  }
}

// atomtypes (n,6) -> 2-layer MLP -> out (n,6)
__global__ void tt_kernel(const float* __restrict__ at_in,
                          const float* __restrict__ w1, const float* __restrict__ b1,
                          const float* __restrict__ w2, const float* __restrict__ b2,
                          float* __restrict__ out, int n){
  int i = blockIdx.x*blockDim.x + threadIdx.x;
  if (i >= n) return;
  float x[D], h[D];
  #pragma unroll
  for (int j=0;j<D;j++) x[j] = at_in[i*D+j];
  #pragma unroll
  for (int o=0;o<D;o++){
    float acc = b1[o];
    #pragma unroll
    for (int j=0;j<D;j++) acc += w1[o*D+j]*x[j];
    h[o] = lrelu(acc);
  }
  #pragma unroll
  for (int o=0;o<D;o++){
    float acc = b2[o];
    #pragma unroll
    for (int j=0;j<D;j++) acc += w2[o*D+j]*h[j];
    out[i*D+o] = acc;
  }
}

// QW independent ascending value-sorts across 64 lanes (ILP-batched)
__device__ __forceinline__ void sort64fq(float (&v)[QW], int lane){
  #pragma unroll
  for (int k = 2; k <= 64; k <<= 1){
    #pragma unroll
    for (int j = k >> 1; j >= 1; j >>= 1){
      bool dir = ((lane & j) == 0) == ((lane & k) == 0);
      #pragma unroll
      for (int q = 0; q < QW; ++q){
        float o = __shfl_xor(v[q], j);
        v[q] = dir ? fminf(v[q], o) : fmaxf(v[q], o);
      }
    }
  }
}

// ascending lexicographic (d, i) bitonic sort across 64 lanes
__device__ __forceinline__ void sort64pair(float& d, int& i, int lane){
  #pragma unroll
  for (int k = 2; k <= 64; k <<= 1){
    #pragma unroll
    for (int j = k >> 1; j >= 1; j >>= 1){
      float od = __shfl_xor(d, j);
      int   oi = __shfl_xor(i, j);
      bool lower = (lane & j) == 0;
      bool asc   = (lane & k) == 0;
      bool oless = (od < d) || (od == d && oi < i);
      bool take  = (lower == asc) ? oless : !oless;
      d = take ? od : d;
      i = take ? oi : i;
    }
  }
}

// KNN v7: R9's structure + depth-PF rotating register prefetch in both scan
// passes (hides ~200cy L2-hit latency under ~256cy of VALU per group).
// Pass 1: per-lane e-min per query -> T = KSEL-th smallest of 64 lane-mins
// (64 disjoint witnesses) + MARGIN. Pass 2: survivors -> LDS slots via
// rare-path atomicAdd (unordered; phase 3 sorts). Phase 3: exact
// contract-off lex (d2, idx) sort across lanes, emit KOUT from OUT_OFF.
template<int KSEL, int OUT_OFF>
__global__ __launch_bounds__(256)
void knn7_kernel(const float4* __restrict__ candP, int ncand,
                 const float4* __restrict__ qarr, int nq,
                 int* __restrict__ oidx, float* __restrict__ odist){
  __shared__ float4 qs[QBLK];
  __shared__ ushort slots[4][QW][CAP];
  __shared__ int    scnt[4][QW];

  const int tid  = threadIdx.x;
  const int w    = tid >> 6;
  const int lane = tid & 63;

  if (tid < QBLK){
    int qg = blockIdx.x*QBLK + tid;
    qs[tid] = qarr[qg < nq ? qg : nq-1];
  }
  if (lane < QW) scnt[w][lane] = 0;
  __syncthreads();

  float q2x[QW], q2y[QW], q2z[QW];
  #pragma unroll
  for (int q = 0; q < QW; ++q){
    float4 v = qs[w*QW + q];
    q2x[q] = -2.f*v.x; q2y[q] = -2.f*v.y; q2z[q] = -2.f*v.z;
  }

  const float4* __restrict__ cl = candP + lane;

  // ---------------- pass 1: per-lane e-min per query (PF-pipelined) ------
  float mn[QW];
  #pragma unroll
  for (int q = 0; q < QW; ++q) mn[q] = FLT_MAX;

  {
    float4 c[PF];
    #pragma unroll
    for (int u = 0; u < PF; ++u) c[u] = cl[u*64];
    for (int it = 0; it < NITER; it += PF){
      float4 nx[PF];
      const int nb = (it + PF < NITER) ? (it + PF) : 0;   // tail: reload start
      #pragma unroll
      for (int u = 0; u < PF; ++u) nx[u] = cl[(nb + u)*64];
      #pragma unroll
      for (int u = 0; u < PF; ++u){
        #pragma unroll
        for (int q = 0; q < QW; ++q){
          float e = fmaf(q2x[q], c[u].x, fmaf(q2y[q], c[u].y, fmaf(q2z[q], c[u].z, c[u].w)));
          mn[q] = fminf(mn[q], e);
        }
      }
      #pragma unroll
      for (int u = 0; u < PF; ++u) c[u] = nx[u];
    }
  }

  // threshold per query: KSEL-th smallest lane-min + margin
  sort64fq(mn, lane);
  float T[QW];
  #pragma unroll
  for (int q = 0; q < QW; ++q) T[q] = __shfl(mn[q], KSEL-1) + MARGIN;

  // ---------------- pass 2: collect survivors (PF-pipelined) -------------
  {
    float4 c[PF];
    #pragma unroll
    for (int u = 0; u < PF; ++u) c[u] = cl[u*64];
    for (int it = 0; it < NITER; it += PF){
      float4 nx[PF];
      const int nb = (it + PF < NITER) ? (it + PF) : 0;
      #pragma unroll
      for (int u = 0; u < PF; ++u) nx[u] = cl[(nb + u)*64];
      #pragma unroll
      for (int u = 0; u < PF; ++u){
        const int j = (it + u)*64 + lane;
        #pragma unroll
        for (int q = 0; q < QW; ++q){
          float e = fmaf(q2x[q], c[u].x, fmaf(q2y[q], c[u].y, fmaf(q2z[q], c[u].z, c[u].w)));
          if (e <= T[q]){
            int ofs = atomicAdd(&scnt[w][q], 1);
            if (ofs < CAP) slots[w][q][ofs] = (ushort)j;
          }
        }
      }
      #pragma unroll
      for (int u = 0; u < PF; ++u) c[u] = nx[u];
    }
  }

  // ---------------- phase 3: exact per-query select ----------------
  for (int q = 0; q < QW; ++q){
    const int qgq = blockIdx.x*QBLK + w*QW + q;
    if (qgq >= nq) continue;                 // wave-uniform
    const float4 qv = qs[w*QW + q];
    const int C = scnt[w][q];

    if (C <= CAP){
      int g = INT_MAX; float d2 = FLT_MAX;
      if (lane < C){
        g = slots[w][q][lane];
        float4 cp = candP[g];
        {
#pragma clang fp contract(off)
          float dot = qv.x*cp.x + qv.y*cp.y + qv.z*cp.z;
          d2 = (qv.w + cp.w) - 2.0f*dot;
        }
      }
      sort64pair(d2, g, lane);
      if (lane >= OUT_OFF && lane < OUT_OFF + KOUT){
        float4 cp = candP[g];
        float dist;
        {
#pragma clang fp contract(off)
          float dx = qv.x-cp.x, dy = qv.y-cp.y, dz = qv.z-cp.z;
          dist = (dx*dx + dy*dy) + dz*dz;
        }
        oidx[(size_t)qgq*KOUT + (lane-OUT_OFF)]  = g;
        odist[(size_t)qgq*KOUT + (lane-OUT_OFF)] = dist;
      }
    } else if (lane == 0){
      // astronomically rare slot overflow: serial exact full scan
      float bd[KSEL]; int bi[KSEL];
      #pragma unroll
      for (int t=0;t<KSEL;t++){ bd[t]=FLT_MAX; bi[t]=INT_MAX; }
      float cmd = FLT_MAX; int cmi = INT_MAX;
      for (int jj = 0; jj < ncand; ++jj){
        float4 cp = candP[jj];
        float d2;
        {
#pragma clang fp contract(off)
          float dot = qv.x*cp.x + qv.y*cp.y + qv.z*cp.z;
          d2 = (qv.w + cp.w) - 2.0f*dot;
        }
        if (d2 < cmd || (d2 == cmd && jj < cmi)){
          int rt = 0; float rmd=-FLT_MAX; int rmi=-1;
          for (int t=0;t<KSEL;t++){
            if (bd[t] > rmd || (bd[t]==rmd && bi[t]>rmi)){ rmd=bd[t]; rmi=bi[t]; rt=t; }
          }
          bd[rt]=d2; bi[rt]=jj;
          cmd=-FLT_MAX; cmi=-1;
          for (int t=0;t<KSEL;t++){
            if (bd[t] > cmd || (bd[t]==cmd && bi[t]>cmi)){ cmd=bd[t]; cmi=bi[t]; }
          }
        }
      }
      for (int t=0;t<KSEL;t++){
        int rt=-1; float mnd=FLT_MAX; int mni=INT_MAX;
        for (int u2=0;u2<KSEL;u2++){
          if (bd[u2] < mnd || (bd[u2]==mnd && bi[u2]<mni)){ mnd=bd[u2]; mni=bi[u2]; rt=u2; }
        }
        bd[rt]=FLT_MAX; bi[rt]=INT_MAX;
        if (t >= OUT_OFF){
          float4 cp = candP[mni];
          float dist;
          {
#pragma clang fp contract(off)
            float dx=qv.x-cp.x, dy=qv.y-cp.y, dz=qv.z-cp.z;
            dist = (dx*dx + dy*dy) + dz*dz;
          }
          oidx[(size_t)qgq*KOUT + (t-OUT_OFF)]  = mni;
          odist[(size_t)qgq*KOUT + (t-OUT_OFF)] = dist;
        }
      }
    }
  }
}

// One message-passing block: out = self + lrelu(groupnorm(sum_k MLP(feat_k)))
// 4 threads per point: each handles 4 of the 16 neighbors, shfl-reduce.
template<bool SELF_ONES>
__global__ __launch_bounds__(256)
void mp_kernel(const float* __restrict__ self_feat,
               const float* __restrict__ nb_src,
               const int* __restrict__ idx,
               const float* __restrict__ dists,
               const float* __restrict__ w1g, const float* __restrict__ b1g,
               const float* __restrict__ w2g, const float* __restrict__ b2g,
               const float* __restrict__ gam, const float* __restrict__ bet,
               float* __restrict__ out, int n){
  __shared__ float w1[H*H], b1v[H], w2[D*H], b2v[D], gm[D], bt[D];
  for (int t=threadIdx.x; t<H*H; t+=blockDim.x) w1[t]=w1g[t];
  if (threadIdx.x < H) b1v[threadIdx.x]=b1g[threadIdx.x];
  for (int t=threadIdx.x; t<D*H; t+=blockDim.x) w2[t]=w2g[t];
  if (threadIdx.x < D){
    b2v[threadIdx.x]=b2g[threadIdx.x];
    gm[threadIdx.x]=gam[threadIdx.x];
    bt[threadIdx.x]=bet[threadIdx.x];
  }
  __syncthreads();
  int tt = blockIdx.x*blockDim.x + threadIdx.x;
  int p = tt >> 2, sub = tt & 3;
  if (p >= n) return;

  float s[D];
  #pragma unroll
  for (int j=0;j<D;j++) s[j] = SELF_ONES ? 1.0f : self_feat[p*D+j];
  float msg[D] = {0,0,0,0,0,0};

  #pragma unroll
  for (int u=0;u<KOUT/4;u++){
    int k = u*4 + sub;
    int j = idx[p*KOUT+k];
    float dd = dists[p*KOUT+k];
    float f[H];
    #pragma unroll
    for (int c=0;c<D;c++) f[c]=s[c];
    #pragma unroll
    for (int c=0;c<D;c++) f[D+c]=nb_src[j*D+c];
    f[2*D]=dd;
    float h[H];
    #pragma unroll
    for (int o=0;o<H;o++){
      float acc=b1v[o];
      #pragma unroll
      for (int c=0;c<H;c++) acc += w1[o*H+c]*f[c];
      h[o]=lrelu(acc);
    }
    #pragma unroll
    for (int o=0;o<D;o++){
      float acc=b2v[o];
      #pragma unroll
      for (int c=0;c<H;c++) acc += w2[o*H+c]*h[c];
      msg[o]+=acc;
    }
  }

  #pragma unroll
  for (int c=0;c<D;c++){
    msg[c] += __shfl_xor(msg[c], 1);
    msg[c] += __shfl_xor(msg[c], 2);
  }

  if (sub == 0){
    float y[D];
    #pragma unroll
    for (int gi=0; gi<2; gi++){
      float m0=msg[gi*3+0], m1=msg[gi*3+1], m2=msg[gi*3+2];
      float mu = ((m0+m1)+m2) / 3.0f;
      float d0=m0-mu, d1=m1-mu, d2v=m2-mu;
      float var = ((d0*d0 + d1*d1) + d2v*d2v) / 3.0f;
      float inv = 1.0f / sqrtf(var + GEPS);
      y[gi*3+0] = d0*inv;
      y[gi*3+1] = d1*inv;
      y[gi*3+2] = d2v*inv;
    }
    #pragma unroll
    for (int c=0;c<D;c++){
      float vv = y[c]*gm[c] + bt[c];
      out[p*D+c] = s[c] + lrelu(vv);
    }
  }
}

extern "C" void kernel_launch(void* const* d_in, const int* in_sizes, int n_in,
                              void* d_out, int out_size, void* d_ws, size_t ws_size,
                              hipStream_t stream){
  const float* xyz       = (const float*)d_in[0];
  const float* atom_xyz  = (const float*)d_in[1];
  const float* atomtypes = (const float*)d_in[2];
  const float* tt_w1 = (const float*)d_in[5];
  const float* tt_b1 = (const float*)d_in[6];
  const float* tt_w2 = (const float*)d_in[7];
  const float* tt_b2 = (const float*)d_in[8];
  const float* aa_w1 = (const float*)d_in[9];
  const float* aa_b1 = (const float*)d_in[10];
  const float* aa_w2 = (const float*)d_in[11];
  const float* aa_b2 = (const float*)d_in[12];
  const float* aa_gamma = (const float*)d_in[13];
  const float* aa_beta  = (const float*)d_in[14];
  const float* em_w1 = (const float*)d_in[15];
  const float* em_b1 = (const float*)d_in[16];
  const float* em_w2 = (const float*)d_in[17];
  const float* em_b2 = (const float*)d_in[18];
  const float* em_gamma = (const float*)d_in[19];
  const float* em_beta  = (const float*)d_in[20];

  const int n_pts = in_sizes[0]/3;
  const int n_at  = in_sizes[1]/3;

  char* ws = (char*)d_ws;
  float4* candP = (float4*)ws; ws += (size_t)MPAD*sizeof(float4);
  float4* ptsP  = (float4*)ws; ws += (size_t)n_pts*sizeof(float4);
  float* fa   = (float*)ws; ws += (size_t)n_at*D*4;
  float* fb   = (float*)ws; ws += (size_t)n_at*D*4;
  int*   idxA = (int*)ws;   ws += (size_t)n_at*KOUT*4;
  float* distA= (float*)ws; ws += (size_t)n_at*KOUT*4;
  int*   idxP = (int*)ws;   ws += (size_t)n_pts*KOUT*4;
  float* distP= (float*)ws; ws += (size_t)n_pts*KOUT*4;
  float* ea   = (float*)ws; ws += (size_t)n_pts*D*4;
  float* eb   = (float*)ws; ws += (size_t)n_pts*D*4;
  float* outf = (float*)d_out;

  pack_kernel<<<(MPAD+255)/256,256,0,stream>>>(atom_xyz, candP, n_at, MPAD);
  pack_kernel<<<(n_pts+255)/256,256,0,stream>>>(xyz, ptsP, n_pts, n_pts);

  tt_kernel<<<(n_at+255)/256,256,0,stream>>>(atomtypes, tt_w1,tt_b1,tt_w2,tt_b2, fa, n_at);

  // ---- atom-atom KNN (k=17, drop self) ----
  knn7_kernel<17,1><<<(n_at+QBLK-1)/QBLK,256,0,stream>>>(
      candP, n_at, candP, n_at, idxA, distA);

  mp_kernel<false><<<(n_at*4+255)/256,256,0,stream>>>(fa, fa, idxA, distA,
      aa_w1+0*H*H, aa_b1+0*H, aa_w2+0*D*H, aa_b2+0*D, aa_gamma+0*D, aa_beta+0*D, fb, n_at);
  mp_kernel<false><<<(n_at*4+255)/256,256,0,stream>>>(fb, fb, idxA, distA,
      aa_w1+1*H*H, aa_b1+1*H, aa_w2+1*D*H, aa_b2+1*D, aa_gamma+1*D, aa_beta+1*D, fa, n_at);
  mp_kernel<false><<<(n_at*4+255)/256,256,0,stream>>>(fa, fa, idxA, distA,
      aa_w1+2*H*H, aa_b1+2*H, aa_w2+2*D*H, aa_b2+2*D, aa_gamma+2*D, aa_beta+2*D, fb, n_at);
  // final atom features in fb

  // ---- point-atom KNN (k=16) ----
  knn7_kernel<16,0><<<(n_pts+QBLK-1)/QBLK,256,0,stream>>>(
      candP, n_at, ptsP, n_pts, idxP, distP);

  mp_kernel<true ><<<(n_pts*4+255)/256,256,0,stream>>>(nullptr, fb, idxP, distP,
      em_w1+0*H*H, em_b1+0*H, em_w2+0*D*H, em_b2+0*D, em_gamma+0*D, em_beta+0*D, ea, n_pts);
  mp_kernel<false><<<(n_pts*4+255)/256,256,0,stream>>>(ea, fb, idxP, distP,
      em_w1+1*H*H, em_b1+1*H, em_w2+1*D*H, em_b2+1*D, em_gamma+1*D, em_beta+1*D, eb, n_pts);
  mp_kernel<false><<<(n_pts*4+255)/256,256,0,stream>>>(eb, fb, idxP, distP,
      em_w1+2*H*H, em_b1+2*H, em_w2+2*D*H, em_b2+2*D, em_gamma+2*D, em_beta+2*D, outf, n_pts);
}